// Round 3
// baseline (402.044 us; speedup 1.0000x reference)
//
#include <hip/hip_runtime.h>

#define BS 256
#define NQ 512
#define NC 128
#define NP 256
#define NG 128
#define TQ 32
#define BIGC 1.0e6f
#define EPSC 1e-6f

// ws layout (floats):
//   [0, BS*NP)                    : lse per (b,p)                      256 KB
//   [BS*NP, BS*NP + BS*8*2*NQ)    : per-block partials [b][blk8][2][NQ]  8 MB
//     [...][0][q] = sum_p P, [...][1][q] = sum_p log1p(-Pc)

// ---------------- K1: one pass over att: lse + per-q totals ----------------
// 512 threads, 16 lanes per person-row, 32 rows per block, 8 blocks per batch.
__global__ __launch_bounds__(512) void pre_kernel(const float* __restrict__ att,
                                                  float* __restrict__ lse,
                                                  float* __restrict__ part) {
    __shared__ float szS[NQ];
    __shared__ float slS[NQ];
    const int t   = threadIdx.x;
    const int blk = blockIdx.x;          // b*8 + slab
    const int b   = blk >> 3;
    const int p   = (blk & 7) * 32 + (t >> 4);
    const int sub = t & 15;

    szS[t] = 0.f;
    slS[t] = 0.f;

    const float4* a4 = (const float4*)(att + ((size_t)(b * NP + p)) * NQ);
    float4 v[8];
#pragma unroll
    for (int i = 0; i < 8; ++i) v[i] = a4[sub + 16 * i];   // full row in regs

    float mx = -1e30f;
#pragma unroll
    for (int i = 0; i < 8; ++i)
        mx = fmaxf(mx, fmaxf(fmaxf(v[i].x, v[i].y), fmaxf(v[i].z, v[i].w)));
#pragma unroll
    for (int off = 1; off < 16; off <<= 1) mx = fmaxf(mx, __shfl_xor(mx, off, 64));

    float s = 0.f;
#pragma unroll
    for (int i = 0; i < 8; ++i) {
        v[i].x = __expf(v[i].x - mx); v[i].y = __expf(v[i].y - mx);
        v[i].z = __expf(v[i].z - mx); v[i].w = __expf(v[i].w - mx);
        s += v[i].x + v[i].y + v[i].z + v[i].w;
    }
#pragma unroll
    for (int off = 1; off < 16; off <<= 1) s += __shfl_xor(s, off, 64);
    if (sub == 0) lse[b * NP + p] = mx + __logf(s);
    const float inv = 1.f / s;

    __syncthreads();   // szS/slS zeroed

    // per-element: P and log1p(-Pc); reduce across the wave's 4 rows, accumulate
#pragma unroll
    for (int i = 0; i < 8; ++i) {
        float Pv[4] = {v[i].x * inv, v[i].y * inv, v[i].z * inv, v[i].w * inv};
#pragma unroll
        for (int c = 0; c < 4; ++c) {
            float P = Pv[c];
            float Pc = fminf(fmaxf(P, EPSC), 1.f - EPSC);
            float l = __logf(1.f - Pc);
            P += __shfl_xor(P, 16, 64); P += __shfl_xor(P, 32, 64);
            l += __shfl_xor(l, 16, 64); l += __shfl_xor(l, 32, 64);
            if ((t & 63) < 16) {
                const int q = 64 * i + 4 * sub + c;
                atomicAdd(&szS[q], P);
                atomicAdd(&slS[q], l);
            }
        }
    }
    __syncthreads();

    float* basep = part + (size_t)blk * 2 * NQ;
    basep[t]      = szS[t];
    basep[NQ + t] = slS[t];
}

// ---------------- K2: cost for a (b, 32-query) tile ----------------
__global__ __launch_bounds__(256) void cost_kernel(
    const float* __restrict__ predAct,   // [BS,NQ,NC]
    const float* __restrict__ att,       // [BS,NP,NQ]
    const int*   __restrict__ actIds,    // [BS,NG]
    const int*   __restrict__ grpIds,    // [BS,NP]
    const float* __restrict__ lseAtt,    // [BS*NP]
    const float* __restrict__ part,      // [BS][8][2][NQ]
    float*       __restrict__ out)       // [BS,NQ,NG]
{
    __shared__ float xS[NP * TQ];        // x = logP, rows in CSR-permuted order (32 KB)
    __shared__ float lseS[NP];
    __shared__ float lseAct[TQ];
    __shared__ float szG[TQ], slG[TQ];
    __shared__ int   gidS[NP];
    __shared__ int   rankS[NP];
    __shared__ int   aidS[NG];
    __shared__ int   cntS[NG];
    __shared__ int   startS[NG];

    const int b  = blockIdx.x >> 4;
    const int q0 = (blockIdx.x & 15) * TQ;
    const int t  = threadIdx.x;

    // prefetch att tile into registers (consumed after CSR build)
    const int pr  = t >> 3;
    const int qo4 = (t & 7) * 4;
    float4 v[8];
#pragma unroll
    for (int iter = 0; iter < 8; ++iter)
        v[iter] = *(const float4*)(att + ((size_t)(b * NP + iter * 32 + pr)) * NQ + q0 + qo4);

    // small staging
    lseS[t] = lseAtt[b * NP + t];
    gidS[t] = grpIds[b * NP + t];
    if (t < NG) { aidS[t] = actIds[b * NG + t]; cntS[t] = 0; }
    if (t < 2 * TQ) {   // per-q totals from K1 partials
        const int qo = t & 31, which = t >> 5;
        const float* pb = part + ((size_t)(b * 8)) * 2 * NQ + (size_t)which * NQ + q0 + qo;
        float s = 0.f;
#pragma unroll
        for (int k = 0; k < 8; ++k) s += pb[(size_t)k * 2 * NQ];
        if (which == 0) szG[qo] = s; else slG[qo] = s;
    }
    __syncthreads();

    const int myPos = atomicAdd(&cntS[gidS[t]], 1);
    __syncthreads();

    // single-wave exclusive scan of group counts (lane owns 2 adjacent groups)
    if (t < 64) {
        const int c0 = cntS[2 * t], c1 = cntS[2 * t + 1];
        const int ps = c0 + c1;
        int s = ps;
#pragma unroll
        for (int off = 1; off < 64; off <<= 1) {
            const int w = __shfl_up(s, off, 64);
            if (t >= off) s += w;
        }
        startS[2 * t]     = s - ps;
        startS[2 * t + 1] = s - ps + c0;
    }
    __syncthreads();
    rankS[t] = startS[gidS[t]] + myPos;
    __syncthreads();

    // phase A: subtract lse, store rows at permuted rank (pure streaming)
#pragma unroll
    for (int iter = 0; iter < 8; ++iter) {
        const int p  = iter * 32 + pr;
        const float l = lseS[p];
        const int rr = rankS[p];
        float x[4] = {v[iter].x - l, v[iter].y - l, v[iter].z - l, v[iter].w - l};
        *(float4*)(xS + rr * TQ + qo4) = *(float4*)x;
    }

    // phase A2: activity row LSEs (one wave per row)
    const int wv = t >> 6, ln = t & 63;
    for (int r = wv; r < TQ; r += 4) {
        const float* rowp = predAct + ((size_t)(b * NQ + q0 + r)) * NC;
        const float v0 = rowp[ln], v1 = rowp[ln + 64];
        float mx = fmaxf(v0, v1);
#pragma unroll
        for (int off = 1; off < 64; off <<= 1) mx = fmaxf(mx, __shfl_xor(mx, off, 64));
        float s = __expf(v0 - mx) + __expf(v1 - mx);
#pragma unroll
        for (int off = 1; off < 64; off <<= 1) s += __shfl_xor(s, off, 64);
        if (ln == 0) lseAct[r] = mx + __logf(s);
    }
    __syncthreads();

    // phase C: gather per (group, query); member rows are sequential in xS
    const float* actBase = predAct + ((size_t)(b * NQ + q0)) * NC;
#pragma unroll
    for (int rep = 0; rep < 4; ++rep) {
        const int idx = rep * 256 + t;
        const int qo  = idx & 31;          // lane-fast -> conflict-free xS banks
        const int g4  = (idx >> 5) * 4;
        const float sl = slG[qo], pz = szG[qo], la = lseAct[qo];
        float res[4];
#pragma unroll
        for (int j = 0; j < 4; ++j) {
            const int g  = g4 + j;
            const int m  = cntS[g];
            const int st = startS[g];
            float ms = 0.f, ml = 0.f;
            for (int i = 0; i < m; ++i) {
                const float x = xS[(st + i) * TQ + qo];   // sequential rows, no chase
                ms += x;
                const float e = __expf(x);
                const float c = fminf(fmaxf(e, EPSC), 1.f - EPSC);
                ml += __logf(1.f - c);
            }
            const float mf  = (float)m;
            const float nmf = (float)(NP - m);
            float grp = -ms / fmaxf(mf, 1.f) - (sl - ml) / fmaxf(nmf, 1.f);
            float szc = fabsf(pz - mf) * (1.f / (float)NP);
            if (m == 0) { grp = BIGC; szc = BIGC; }
            const float av = actBase[(size_t)qo * NC + aidS[g]];   // L1-hot gather
            res[j] = grp + (la - av) + szc;
        }
        *(float4*)(out + ((size_t)(b * NQ + q0 + qo)) * NG + g4) = *(float4*)res;
    }
}

extern "C" void kernel_launch(void* const* d_in, const int* in_sizes, int n_in,
                              void* d_out, int out_size, void* d_ws, size_t ws_size,
                              hipStream_t stream) {
    const float* predAct = (const float*)d_in[0];
    const float* att     = (const float*)d_in[1];
    const int*   actIds  = (const int*)d_in[2];
    const int*   grpIds  = (const int*)d_in[3];
    float*       out     = (float*)d_out;
    float*       lse     = (float*)d_ws;                 // BS*NP floats
    float*       part    = lse + (size_t)BS * NP;        // BS*8*2*NQ floats (8 MB)

    pre_kernel<<<BS * 8, 512, 0, stream>>>(att, lse, part);
    cost_kernel<<<BS * (NQ / TQ), 256, 0, stream>>>(predAct, att, actIds, grpIds, lse, part, out);
}

// Round 4
// 320.983 us; speedup vs baseline: 1.2525x; 1.2525x over previous
//
#include <hip/hip_runtime.h>

#define BS 256
#define NQ 512
#define NC 128
#define NP 256
#define NG 128
#define TQ 32
#define BIGC 1.0e6f
#define EPSC 1e-6f

// ws layout (floats):
//   [0, BS*NP)                 : lse per (b,p)
//   [BS*NP, +BS*8*2*NQ)        : per-slab partials [b][slab8][2][NQ]
//     [..][0][q] = sum_p P , [..][1][q] = sum_p log1p(-Pc)

// ---------------- K1: lse + per-q totals, one pass over att ----------------
// 512 thr, 16 lanes/row, 32 rows (one slab) per block, 8 slabs per batch.
__global__ __launch_bounds__(512) void pre_kernel(const float* __restrict__ att,
                                                  float* __restrict__ lse,
                                                  float* __restrict__ part) {
    __shared__ float attS[32 * NQ];   // exp(v - rowmax), 64 KB
    __shared__ float invS[32];        // 1/rowsum
    const int t   = threadIdx.x;
    const int blk = blockIdx.x;       // b*8 + slab
    const int b   = blk >> 3;
    const int r   = t >> 4;           // row 0..31
    const int p   = (blk & 7) * 32 + r;
    const int sub = t & 15;

    const float4* a4 = (const float4*)(att + ((size_t)(b * NP + p)) * NQ);
    float4 v[8];
#pragma unroll
    for (int i = 0; i < 8; ++i) v[i] = a4[sub + 16 * i];

    float mx = -1e30f;
#pragma unroll
    for (int i = 0; i < 8; ++i)
        mx = fmaxf(mx, fmaxf(fmaxf(v[i].x, v[i].y), fmaxf(v[i].z, v[i].w)));
#pragma unroll
    for (int off = 1; off < 16; off <<= 1) mx = fmaxf(mx, __shfl_xor(mx, off, 64));

    float s = 0.f;
#pragma unroll
    for (int i = 0; i < 8; ++i) {
        v[i].x = __expf(v[i].x - mx); v[i].y = __expf(v[i].y - mx);
        v[i].z = __expf(v[i].z - mx); v[i].w = __expf(v[i].w - mx);
        s += v[i].x + v[i].y + v[i].z + v[i].w;
        *(float4*)(attS + r * NQ + 4 * sub + 64 * i) = v[i];
    }
#pragma unroll
    for (int off = 1; off < 16; off <<= 1) s += __shfl_xor(s, off, 64);
    if (sub == 0) {
        invS[r] = 1.f / s;
        lse[b * NP + p] = mx + __logf(s);
    }
    __syncthreads();

    // pass 2: thread t owns column q=t; plain conflict-free LDS reads, no atomics
    float sz = 0.f, sl = 0.f;
#pragma unroll 8
    for (int pp = 0; pp < 32; ++pp) {
        const float P = attS[pp * NQ + t] * invS[pp];
        sz += P;
        const float c = fminf(fmaxf(P, EPSC), 1.f - EPSC);
        sl += __logf(1.f - c);
    }
    float* basep = part + (size_t)blk * 2 * NQ;
    basep[t]      = sz;
    basep[NQ + t] = sl;
}

// ---------------- K2: cost for a (b, 32-query) tile; 512 threads ----------------
__global__ __launch_bounds__(512) void cost_kernel(
    const float* __restrict__ predAct,   // [BS,NQ,NC]
    const float* __restrict__ att,       // [BS,NP,NQ]
    const int*   __restrict__ actIds,    // [BS,NG]
    const int*   __restrict__ grpIds,    // [BS,NP]
    const float* __restrict__ lseAtt,    // [BS*NP]
    const float* __restrict__ part,      // [BS][8][2][NQ]
    float*       __restrict__ out)       // [BS,NQ,NG]
{
    __shared__ float xS[NP * TQ];        // x = logP, CSR-permuted rows (32 KB)
    __shared__ float lS[NP * TQ];        // log1p(-Pc), same layout (32 KB)
    __shared__ float lseS[NP];
    __shared__ float lseAct[TQ];
    __shared__ float szG[TQ], slG[TQ];
    __shared__ int   gidS[NP];
    __shared__ int   rankS[NP];
    __shared__ int   aidS[NG];
    __shared__ int   cntS[NG];
    __shared__ int   startS[NG];

    const int b  = blockIdx.x >> 4;
    const int q0 = (blockIdx.x & 15) * TQ;
    const int t  = threadIdx.x;

    // prefetch att tile (4 x float4) — consumed in phase A after CSR build
    const int pr  = t >> 3;              // 64 rows per iteration
    const int qo4 = (t & 7) * 4;
    float4 v[4];
#pragma unroll
    for (int it = 0; it < 4; ++it)
        v[it] = *(const float4*)(att + ((size_t)(b * NP + it * 64 + pr)) * NQ + q0 + qo4);

    // prefetch predAct rows for the activity LSEs (wave wv owns rows wv+8k)
    const int wv = t >> 6, ln = t & 63;
    float pa0[4], pa1[4];
#pragma unroll
    for (int k = 0; k < 4; ++k) {
        const float* rowp = predAct + ((size_t)(b * NQ + q0 + wv + 8 * k)) * NC;
        pa0[k] = rowp[ln]; pa1[k] = rowp[ln + 64];
    }

    // small staging
    if (t < NP) { lseS[t] = lseAtt[b * NP + t]; gidS[t] = grpIds[b * NP + t]; }
    if (t < NG) { aidS[t] = actIds[b * NG + t]; cntS[t] = 0; }
    if (t < 2 * TQ) {   // per-q totals from K1 partials
        const int qo = t & 31, which = t >> 5;
        const float* pb = part + ((size_t)(b * 8)) * 2 * NQ + (size_t)which * NQ + q0 + qo;
        float s = 0.f;
#pragma unroll
        for (int k = 0; k < 8; ++k) s += pb[(size_t)k * 2 * NQ];
        if (which == 0) szG[qo] = s; else slG[qo] = s;
    }
    __syncthreads();

    int myPos = 0;
    if (t < NP) myPos = atomicAdd(&cntS[gidS[t]], 1);
    __syncthreads();

    // single-wave exclusive scan of group counts (lane owns 2 adjacent groups)
    if (t < 64) {
        const int c0 = cntS[2 * t], c1 = cntS[2 * t + 1];
        const int ps = c0 + c1;
        int s = ps;
#pragma unroll
        for (int off = 1; off < 64; off <<= 1) {
            const int w = __shfl_up(s, off, 64);
            if (t >= off) s += w;
        }
        startS[2 * t]     = s - ps;
        startS[2 * t + 1] = s - ps + c0;
    }
    __syncthreads();
    if (t < NP) rankS[t] = startS[gidS[t]] + myPos;
    __syncthreads();

    // phase A: x + log1p(-P) tiles at permuted rank (transcendentals happen HERE)
#pragma unroll
    for (int it = 0; it < 4; ++it) {
        const int p  = it * 64 + pr;
        const float l = lseS[p];
        const int rr = rankS[p];
        float x[4], ll[4];
        const float vv[4] = {v[it].x, v[it].y, v[it].z, v[it].w};
#pragma unroll
        for (int j = 0; j < 4; ++j) {
            x[j] = vv[j] - l;
            const float e = __expf(x[j]);
            const float c = fminf(fmaxf(e, EPSC), 1.f - EPSC);
            ll[j] = __logf(1.f - c);
        }
        *(float4*)(xS + rr * TQ + qo4) = *(float4*)x;
        *(float4*)(lS + rr * TQ + qo4) = *(float4*)ll;
    }

    // phase A2: activity row LSEs (one wave per row, 4 rows/wave)
#pragma unroll
    for (int k = 0; k < 4; ++k) {
        const int r = wv + 8 * k;
        float mx = fmaxf(pa0[k], pa1[k]);
#pragma unroll
        for (int off = 1; off < 64; off <<= 1) mx = fmaxf(mx, __shfl_xor(mx, off, 64));
        float s = __expf(pa0[k] - mx) + __expf(pa1[k] - mx);
#pragma unroll
        for (int off = 1; off < 64; off <<= 1) s += __shfl_xor(s, off, 64);
        if (ln == 0) lseAct[r] = mx + __logf(s);
    }
    __syncthreads();

    // phase C: pure-add gather; member rows sequential in LDS
    const float* actBase = predAct + ((size_t)(b * NQ + q0)) * NC;
#pragma unroll
    for (int rep = 0; rep < 2; ++rep) {
        const int idx = rep * 512 + t;
        const int qo  = idx & 31;          // lane-fast -> conflict-free banks
        const int g4  = (idx >> 5) * 4;
        const float sl = slG[qo], pz = szG[qo], la = lseAct[qo];
        float res[4];
#pragma unroll
        for (int j = 0; j < 4; ++j) {
            const int g  = g4 + j;
            const int m  = cntS[g];
            const int st = startS[g];
            float ms = 0.f, ml = 0.f;
            for (int i = 0; i < m; ++i) {
                ms += xS[(st + i) * TQ + qo];
                ml += lS[(st + i) * TQ + qo];
            }
            const float mf  = (float)m;
            const float nmf = (float)(NP - m);
            float grp = -ms / fmaxf(mf, 1.f) - (sl - ml) / fmaxf(nmf, 1.f);
            float szc = fabsf(pz - mf) * (1.f / (float)NP);
            if (m == 0) { grp = BIGC; szc = BIGC; }
            const float av = actBase[(size_t)qo * NC + aidS[g]];   // L1-hot gather
            res[j] = grp + (la - av) + szc;
        }
        *(float4*)(out + ((size_t)(b * NQ + q0 + qo)) * NG + g4) = *(float4*)res;
    }
}

extern "C" void kernel_launch(void* const* d_in, const int* in_sizes, int n_in,
                              void* d_out, int out_size, void* d_ws, size_t ws_size,
                              hipStream_t stream) {
    const float* predAct = (const float*)d_in[0];
    const float* att     = (const float*)d_in[1];
    const int*   actIds  = (const int*)d_in[2];
    const int*   grpIds  = (const int*)d_in[3];
    float*       out     = (float*)d_out;
    float*       lse     = (float*)d_ws;
    float*       part    = lse + (size_t)BS * NP;

    pre_kernel<<<BS * 8, 512, 0, stream>>>(att, lse, part);
    cost_kernel<<<BS * (NQ / TQ), 512, 0, stream>>>(predAct, att, actIds, grpIds, lse, part, out);
}